// Round 8
// baseline (10892.547 us; speedup 1.0000x reference)
//
#include <hip/hip_runtime.h>

namespace {

constexpr int kB = 32;
constexpr int kT = 64;
constexpr int kH = 1024;
constexpr int kE = 1024;
constexpr int kV = 16000;
constexpr int kG = 4096;  // 4*H

typedef __attribute__((ext_vector_type(8))) short short8v;
typedef __attribute__((ext_vector_type(4))) float f32x4;

__device__ __forceinline__ float sigmoid_f(float x) {
  return 1.0f / (1.0f + __expf(-x));
}
__device__ __forceinline__ unsigned short f2bf(float x) {
  unsigned int u = __builtin_bit_cast(unsigned int, x);
  u = (u + 0x7FFFu + ((u >> 16) & 1u)) >> 16;
  return (unsigned short)u;
}
__device__ __forceinline__ float bf2f(unsigned short h) {
  return __builtin_bit_cast(float, (unsigned int)h << 16);
}

// ---------------- t=0 logits slice ----------------
__global__ void zero_t0_kernel(float* __restrict__ out) {
  int idx = blockIdx.x * blockDim.x + threadIdx.x;
  if (idx >= kB * kV) return;
  int b = idx / kV, v = idx % kV;
  __builtin_nontemporal_store(0.0f, &out[(size_t)b * kT * kV + v]);
}

// JAX outer-index semantics: out[b, 0, output_ids[j, 0]] = 1 for ALL (b, j)
__global__ void ones_t0_kernel(const int* __restrict__ output_ids,
                               float* __restrict__ out) {
  int b = threadIdx.x >> 5;
  int j = threadIdx.x & 31;
  int id = output_ids[j * kT];
  out[(size_t)b * kT * kV + id] = 1.0f;
}

// ---- convert fp32 row-major (R,1024) -> bf16 MFMA B-frag order, 16-row tiles.
__global__ __launch_bounds__(256)
void convert_frag(const float* __restrict__ src, unsigned short* __restrict__ dst,
                  int nchunks) {
  const int idx = blockIdx.x * 256 + threadIdx.x;
  if (idx >= nchunks) return;
  const int lane = idx & 63;
  const int s = (idx >> 6) & 31;
  const int rg = idx >> 11;
  const int row = rg * 16 + (lane & 15);
  const int k = s * 32 + ((lane >> 4) << 3);
  const float4* p = reinterpret_cast<const float4*>(src + (size_t)row * kH + k);
  float4 v0 = p[0], v1 = p[1];
  short8v o;
  o[0] = (short)f2bf(v0.x); o[1] = (short)f2bf(v0.y);
  o[2] = (short)f2bf(v0.z); o[3] = (short)f2bf(v0.w);
  o[4] = (short)f2bf(v1.x); o[5] = (short)f2bf(v1.y);
  o[6] = (short)f2bf(v1.z); o[7] = (short)f2bf(v1.w);
  *reinterpret_cast<short8v*>(dst + (size_t)idx * 8) = o;
}

// ---- convert fp32 gate-matrix (4096,1024) -> cell B-frag order.
// 16 n-cols = 4 gates x 4 units; quad q = ub*2+uq owns units 4q..4q+3.
__global__ __launch_bounds__(256)
void convert_cell(const float* __restrict__ src, unsigned short* __restrict__ dst,
                  int nchunks) {
  const int idx = blockIdx.x * 256 + threadIdx.x;
  if (idx >= nchunks) return;
  const int l = idx & 63;
  const int kstep = (idx >> 6) & 31;
  const int uq = (idx >> 11) & 1;
  const int ub = idx >> 12;
  const int n = l & 15;
  const int row = (n >> 2) * kH + ub * 8 + uq * 4 + (n & 3);
  const int k = kstep * 32 + ((l >> 4) << 3);
  const float4* p = reinterpret_cast<const float4*>(src + (size_t)row * kH + k);
  float4 v0 = p[0], v1 = p[1];
  short8v o;
  o[0] = (short)f2bf(v0.x); o[1] = (short)f2bf(v0.y);
  o[2] = (short)f2bf(v0.z); o[3] = (short)f2bf(v0.w);
  o[4] = (short)f2bf(v1.x); o[5] = (short)f2bf(v1.y);
  o[6] = (short)f2bf(v1.z); o[7] = (short)f2bf(v1.w);
  *reinterpret_cast<short8v*>(dst + (size_t)idx * 8) = o;
}

// ---- gather embedding rows into A-frag bf16 layout.
__global__ __launch_bounds__(256)
void gather_frag(const float* __restrict__ emb, const int* __restrict__ ids,
                 unsigned short* __restrict__ dst, int ntiles) {
  const int idx = blockIdx.x * 256 + threadIdx.x;
  const int lane = idx & 63;
  const int s = (idx >> 6) & 31;
  const int tile = idx >> 11;
  if (tile >= ntiles) return;
  const int m = tile * 16 + (lane & 15);
  const int t = m >> 5, b = m & 31;
  const int id = ids[b * kT + t];
  const int k = s * 32 + ((lane >> 4) << 3);
  const float4* p = reinterpret_cast<const float4*>(emb + (size_t)id * kE + k);
  float4 v0 = p[0], v1 = p[1];
  short8v o;
  o[0] = (short)f2bf(v0.x); o[1] = (short)f2bf(v0.y);
  o[2] = (short)f2bf(v0.z); o[3] = (short)f2bf(v0.w);
  o[4] = (short)f2bf(v1.x); o[5] = (short)f2bf(v1.y);
  o[6] = (short)f2bf(v1.z); o[7] = (short)f2bf(v1.w);
  *reinterpret_cast<short8v*>(dst + (size_t)idx * 8) = o;
}

// ---- proj MFMA: writes xproj in CELL-ORDER: [t][q][m 32][16 = g*4+uu] bf16,
// value = xin . W^T + b0 + b1.
__global__ __launch_bounds__(256)
void proj_mfma(const unsigned short* __restrict__ Af,
               const unsigned short* __restrict__ Bf,
               const float* __restrict__ b0, const float* __restrict__ b1,
               unsigned short* __restrict__ dst, int nmt) {
  const int w = threadIdx.x >> 6, lane = threadIdx.x & 63;
  const int mg = blockIdx.x, ng = blockIdx.y;
  f32x4 acc[4][2] = {};
  const unsigned short* Ab[4];
  const unsigned short* Bb[2];
#pragma unroll
  for (int i = 0; i < 4; ++i) {
    int tile = mg * 4 + i;
    if (tile > nmt - 1) tile = nmt - 1;
    Ab[i] = Af + (size_t)tile * 16384 + lane * 8;
  }
#pragma unroll
  for (int j = 0; j < 2; ++j) {
    const int nt = ng * 8 + w * 2 + j;
    Bb[j] = Bf + (size_t)nt * 16384 + lane * 8;
  }
#pragma unroll 2
  for (int s = 0; s < 32; ++s) {
    short8v a[4], b[2];
#pragma unroll
    for (int i = 0; i < 4; ++i) a[i] = *reinterpret_cast<const short8v*>(Ab[i] + s * 512);
#pragma unroll
    for (int j = 0; j < 2; ++j) b[j] = *reinterpret_cast<const short8v*>(Bb[j] + s * 512);
#pragma unroll
    for (int i = 0; i < 4; ++i)
#pragma unroll
      for (int j = 0; j < 2; ++j)
        acc[i][j] = __builtin_amdgcn_mfma_f32_16x16x32_bf16(a[i], b[j], acc[i][j], 0, 0, 0);
  }
#pragma unroll
  for (int i = 0; i < 4; ++i) {
    const int tile = mg * 4 + i;
    if (tile >= nmt) continue;
    const int mbase = tile * 16 + ((lane >> 4) << 2);
#pragma unroll
    for (int j = 0; j < 2; ++j) {
      const int n = (ng * 8 + w * 2 + j) * 16 + (lane & 15);
      const float bj = b0[n] + b1[n];
      const int g = n >> 10;
      const int u = n & 1023;
      const int q = u >> 2;
      const int uu = u & 3;
#pragma unroll
      for (int r = 0; r < 4; ++r) {
        const int m2 = mbase + r;
        const int t = m2 >> 5, mb = m2 & 31;
        dst[(size_t)t * kB * kG + (size_t)(q * 32 + mb) * 16 + g * 4 + uu] =
            f2bf(acc[i][j][r] + bj);
      }
    }
  }
}

// ---- output GEMM MFMA: XCD-swizzled 1-D grid; 4x4 tiles/wave; two-pass
// 32-row LDS transpose epilogue (33 KB) -> full-line f32x4 NT stores.
__global__ __launch_bounds__(256)
void out_gemm_mfma(const unsigned short* __restrict__ Af,
                   const unsigned short* __restrict__ Bf,
                   const float* __restrict__ bias, float* __restrict__ out) {
  const int w = threadIdx.x >> 6, lane = threadIdx.x & 63;
  // 2016 blocks = 8 XCDs x 252; give each XCD a contiguous swz-range so its
  // L2 holds one ~4MB Wout slice.
  const int bid = blockIdx.x;
  const int swz = (bid & 7) * 252 + (bid >> 3);
  const int mg = swz & 31, ng = swz >> 5;
  __shared__ float LsF[32 * 260];
  f32x4 acc[4][4] = {};
  const unsigned short* Ab[4];
  const unsigned short* Bb[4];
#pragma unroll
  for (int i = 0; i < 4; ++i) {
    int tile = mg * 4 + i;
    if (tile > 125) tile = 125;
    Ab[i] = Af + (size_t)tile * 16384 + lane * 8;
  }
#pragma unroll
  for (int j = 0; j < 4; ++j) {
    int nt = ng * 16 + w * 4 + j;
    if (nt > 999) nt = 999;
    Bb[j] = Bf + (size_t)nt * 16384 + lane * 8;
  }
#pragma unroll 2
  for (int s = 0; s < 32; ++s) {
    short8v a[4], b[4];
#pragma unroll
    for (int i = 0; i < 4; ++i) a[i] = *reinterpret_cast<const short8v*>(Ab[i] + s * 512);
#pragma unroll
    for (int j = 0; j < 4; ++j) b[j] = *reinterpret_cast<const short8v*>(Bb[j] + s * 512);
#pragma unroll
    for (int i = 0; i < 4; ++i)
#pragma unroll
      for (int j = 0; j < 4; ++j)
        acc[i][j] = __builtin_amdgcn_mfma_f32_16x16x32_bf16(a[i], b[j], acc[i][j], 0, 0, 0);
  }
  const int nglob = ng * 256 + lane * 4;
  f32x4 b4 = {0.f, 0.f, 0.f, 0.f};
  if (nglob < kV) b4 = *reinterpret_cast<const f32x4*>(&bias[nglob]);
#pragma unroll
  for (int ph = 0; ph < 2; ++ph) {
    if (ph) __syncthreads();
#pragma unroll
    for (int i2 = 0; i2 < 2; ++i2) {
      const int i = ph * 2 + i2;
      const int r2b = i2 * 16 + ((lane >> 4) << 2);
#pragma unroll
      for (int j = 0; j < 4; ++j) {
        const int nloc = (w * 4 + j) * 16 + (lane & 15);
#pragma unroll
        for (int r = 0; r < 4; ++r) LsF[(r2b + r) * 260 + nloc] = acc[i][j][r];
      }
    }
    __syncthreads();
    if (nglob < kV) {
#pragma unroll
      for (int it = 0; it < 8; ++it) {
        const int r2l = w * 8 + it;
        const int m = mg * 64 + ph * 32 + r2l;
        if (m >= 2016) break;
        f32x4 v = *reinterpret_cast<const f32x4*>(&LsF[r2l * 260 + lane * 4]);
        v += b4;
        const int sd = m >> 5, bb = m & 31;
        f32x4* dst = reinterpret_cast<f32x4*>(
            &out[(size_t)bb * kT * kV + (size_t)(sd + 1) * kV + nglob]);
        __builtin_nontemporal_store(v, dst);
      }
    }
  }
}

// ---- persistent recurrence: 256 blocks x 512 thr, 128 grid-sync'd steps.
// Block q owns unit-quad q of both layers; its 96 KB weight slice lives in
// VGPRs (12x short8v). Cross-XCD step barrier: per-block flag + threadfence.
struct RecurArgs {
  const unsigned short* wih1[2];  // enc, dec (cell layout)
  const unsigned short* whh1[2];
  const unsigned short* whh0[2];
  const unsigned short* xproj[2];  // cell-order bases
  const float* bih1[2];            // layer-1 slices (pre-offset +kG)
  const float* bhh1[2];
  float* c0;
  float* c1;
  unsigned short* h0[2];
  unsigned short* h1[2];
  unsigned short* htop;
  int* flags;  // 256 ints, zeroed per launch
};

#define LOADW(dst, src)                                                      \
  {                                                                          \
    _Pragma("unroll") for (int s_ = 0; s_ < 4; ++s_) dst[s_] =               \
        *reinterpret_cast<const short8v*>((src) + wbase + (size_t)s_ * 512); \
  }

__global__ __launch_bounds__(512, 1)
void lstm_persist(RecurArgs A) {
  const int q = blockIdx.x;
  const int tid = threadIdx.x;
  const int wave = tid >> 6, lane = tid & 63;
  const int ksb = wave * 4;
  // Ls[prod][wave][mt][lane][r]; prod: 0=ih1, 1=hh1, 2=hh0
  __shared__ alignas(16) float Ls[3][8][2][64][4];

  const size_t wbase = ((size_t)(q * 32 + ksb) * 64 + lane) * 8;
  short8v wI[4], wJ[4], wH[4];
  LOADW(wI, A.wih1[0]);
  LOADW(wJ, A.whh1[0]);
  LOADW(wH, A.whh0[0]);

  for (int p = 0; p < 128; ++p) {
    if (p == 64) LOADW(wH, A.whh0[1]);
    if (p == 65) {
      LOADW(wI, A.wih1[1]);
      LOADW(wJ, A.whh1[1]);
    }
    const unsigned short* A0 = A.h0[p & 1];
    const unsigned short* A1 = A.h1[(p + 1) & 1];

    f32x4 aI0 = {0.f, 0.f, 0.f, 0.f}, aI1 = {0.f, 0.f, 0.f, 0.f};
    f32x4 aJ0 = {0.f, 0.f, 0.f, 0.f}, aJ1 = {0.f, 0.f, 0.f, 0.f};
    f32x4 aH0 = {0.f, 0.f, 0.f, 0.f}, aH1 = {0.f, 0.f, 0.f, 0.f};
#pragma unroll
    for (int s = 0; s < 4; ++s) {
      const int ks = ksb + s;
      const short8v a00 =
          *reinterpret_cast<const short8v*>(A0 + (size_t)(ks * 64 + lane) * 8);
      const short8v a01 =
          *reinterpret_cast<const short8v*>(A0 + (size_t)((32 + ks) * 64 + lane) * 8);
      const short8v a10 =
          *reinterpret_cast<const short8v*>(A1 + (size_t)(ks * 64 + lane) * 8);
      const short8v a11 =
          *reinterpret_cast<const short8v*>(A1 + (size_t)((32 + ks) * 64 + lane) * 8);
      aI0 = __builtin_amdgcn_mfma_f32_16x16x32_bf16(a00, wI[s], aI0, 0, 0, 0);
      aI1 = __builtin_amdgcn_mfma_f32_16x16x32_bf16(a01, wI[s], aI1, 0, 0, 0);
      aJ0 = __builtin_amdgcn_mfma_f32_16x16x32_bf16(a10, wJ[s], aJ0, 0, 0, 0);
      aJ1 = __builtin_amdgcn_mfma_f32_16x16x32_bf16(a11, wJ[s], aJ1, 0, 0, 0);
      aH0 = __builtin_amdgcn_mfma_f32_16x16x32_bf16(a00, wH[s], aH0, 0, 0, 0);
      aH1 = __builtin_amdgcn_mfma_f32_16x16x32_bf16(a01, wH[s], aH1, 0, 0, 0);
    }
    *reinterpret_cast<f32x4*>(&Ls[0][wave][0][lane][0]) = aI0;
    *reinterpret_cast<f32x4*>(&Ls[0][wave][1][lane][0]) = aI1;
    *reinterpret_cast<f32x4*>(&Ls[1][wave][0][lane][0]) = aJ0;
    *reinterpret_cast<f32x4*>(&Ls[1][wave][1][lane][0]) = aJ1;
    *reinterpret_cast<f32x4*>(&Ls[2][wave][0][lane][0]) = aH0;
    *reinterpret_cast<f32x4*>(&Ls[2][wave][1][lane][0]) = aH1;
    __syncthreads();

    if (tid < 128) {
      const int m = tid >> 2;   // batch row 0..31
      const int ul = tid & 3;   // unit within quad
      const int u = q * 4 + ul;
      const int mt = m >> 4, r = m & 3;
      const int lm = (m & 12) << 2;
      const int ksu = u >> 5;
      const int lane3 = (m & 15) | (((u >> 3) & 3) << 4);
      const int e = u & 7;
      const size_t fidx = (size_t)((mt * 32 + ksu) * 64 + lane3) * 8 + e;

      if (p <= 126) {  // L0(p)
        const int e0 = (p < kT) ? 0 : 1;
        const unsigned short* xprojc =
            A.xproj[e0] + (size_t)(e0 ? (p - kT) : p) * kB * kG;
        float g0[4];
#pragma unroll
        for (int g = 0; g < 4; ++g) {
          const int ln = (g * 4 + ul) | lm;
          float v = 0.f;
#pragma unroll
          for (int ww = 0; ww < 8; ++ww) v += Ls[2][ww][mt][ln][r];
          v += bf2f(xprojc[(q * 32 + m) * 16 + g * 4 + ul]);
          g0[g] = v;
        }
        const float cold = A.c0[m * kH + u];
        const float cnew = sigmoid_f(g0[1]) * cold + sigmoid_f(g0[0]) * tanhf(g0[2]);
        const float hnew = sigmoid_f(g0[3]) * tanhf(cnew);
        A.c0[m * kH + u] = cnew;
        A.h0[(p + 1) & 1][fidx] = f2bf(hnew);
      }
      if (p >= 1) {  // L1(p-1)
        const int e1 = ((p - 1) < kT) ? 0 : 1;
        float g1[4];
#pragma unroll
        for (int g = 0; g < 4; ++g) {
          const int ln = (g * 4 + ul) | lm;
          float v = 0.f;
#pragma unroll
          for (int ww = 0; ww < 8; ++ww)
            v += Ls[0][ww][mt][ln][r] + Ls[1][ww][mt][ln][r];
          v += A.bih1[e1][g * kH + u] + A.bhh1[e1][g * kH + u];
          g1[g] = v;
        }
        const float cold = A.c1[m * kH + u];
        const float cnew = sigmoid_f(g1[1]) * cold + sigmoid_f(g1[0]) * tanhf(g1[2]);
        const float hnew = sigmoid_f(g1[3]) * tanhf(cnew);
        A.c1[m * kH + u] = cnew;
        const unsigned short hb = f2bf(hnew);
        A.h1[p & 1][fidx] = hb;
        if (p >= kT + 1) A.htop[(size_t)(p - kT - 1) * kB * kH + fidx] = hb;
      }
    }

    // ---- grid barrier: release h/c, signal, wait for all 256 blocks ----
    __threadfence();   // flush this step's writes (device scope)
    __syncthreads();   // all threads of block past their fence
    if (tid == 0)
      __hip_atomic_store(&A.flags[q], p + 1, __ATOMIC_RELEASE,
                         __HIP_MEMORY_SCOPE_AGENT);
    if (wave == 0) {
      const int fb = lane * 4;
      for (;;) {
        int f0 = __hip_atomic_load(&A.flags[fb + 0], __ATOMIC_RELAXED,
                                   __HIP_MEMORY_SCOPE_AGENT);
        int f1 = __hip_atomic_load(&A.flags[fb + 1], __ATOMIC_RELAXED,
                                   __HIP_MEMORY_SCOPE_AGENT);
        int f2 = __hip_atomic_load(&A.flags[fb + 2], __ATOMIC_RELAXED,
                                   __HIP_MEMORY_SCOPE_AGENT);
        int f3 = __hip_atomic_load(&A.flags[fb + 3], __ATOMIC_RELAXED,
                                   __HIP_MEMORY_SCOPE_AGENT);
        const int mn = min(min(f0, f1), min(f2, f3));
        if (__all(mn > p)) break;
        __builtin_amdgcn_s_sleep(2);
      }
    }
    __syncthreads();
    __threadfence();   // acquire: invalidate stale L2 before reading new h
  }
}

}  // namespace

extern "C" void kernel_launch(void* const* d_in, const int* in_sizes, int n_in,
                              void* d_out, int out_size, void* d_ws, size_t ws_size,
                              hipStream_t stream) {
  const int* input_ids = (const int*)d_in[0];
  const int* output_ids = (const int*)d_in[1];
  const float* enc_emb = (const float*)d_in[2];
  const float* enc_Wih = (const float*)d_in[3];
  const float* enc_Whh = (const float*)d_in[4];
  const float* enc_bih = (const float*)d_in[5];
  const float* enc_bhh = (const float*)d_in[6];
  const float* dec_emb = (const float*)d_in[7];
  const float* dec_Wih = (const float*)d_in[8];
  const float* dec_Whh = (const float*)d_in[9];
  const float* dec_bih = (const float*)d_in[10];
  const float* dec_bhh = (const float*)d_in[11];
  const float* Wout = (const float*)d_in[12];
  const float* bout = (const float*)d_in[13];
  float* out = (float*)d_out;
  char* ws = (char*)d_ws;

  const size_t WL = (size_t)kG * kH;  // per-layer weight stride (elems)

  // ---- workspace layout (bytes) ----
  size_t off = 0;
  // Region dead after recurrence; Wout frags alias here (32.77 MB < 37.75 MB)
  unsigned short* wout_frag = (unsigned short*)(ws + 0);
  unsigned short* xproj_enc = (unsigned short*)(ws + off); off += (size_t)kT * kB * kG * 2;
  unsigned short* xin_enc = (unsigned short*)(ws + off); off += (size_t)kT * kB * kH * 2;
  unsigned short* wih0_enc = (unsigned short*)(ws + off); off += WL * 2;
  unsigned short* wih0_dec = (unsigned short*)(ws + off); off += WL * 2;
  // persistent regions
  unsigned short* xproj_dec = (unsigned short*)(ws + off); off += (size_t)(kT - 1) * kB * kG * 2;
  unsigned short* xin_dec = (unsigned short*)(ws + off); off += (size_t)(kT - 1) * kB * kH * 2;
  unsigned short* htop_frag = xin_dec;  // alias: xin_dec dead before decoder starts
  float* c0 = (float*)(ws + off); off += (size_t)kB * kH * 4;
  float* c1 = (float*)(ws + off); off += (size_t)kB * kH * 4;
  unsigned short* h0swz[2];
  unsigned short* h1swz[2];
  h0swz[0] = (unsigned short*)(ws + off); off += (size_t)kB * kH * 2;
  h0swz[1] = (unsigned short*)(ws + off); off += (size_t)kB * kH * 2;
  h1swz[0] = (unsigned short*)(ws + off); off += (size_t)kB * kH * 2;
  h1swz[1] = (unsigned short*)(ws + off); off += (size_t)kB * kH * 2;
  unsigned short* wswz[6];
  for (int i = 0; i < 6; ++i) { wswz[i] = (unsigned short*)(ws + off); off += WL * 2; }
  int* flags = (int*)(ws + off); off += 1024;

  // zero c0,c1 + h frag ping-pong buffers (contiguous) + flags
  (void)hipMemsetAsync(c0, 0, (size_t)kB * kH * (4 + 4 + 2 + 2 + 2 + 2), stream);
  (void)hipMemsetAsync(flags, 0, 1024, stream);

  // one-time weight conversions
  const int wchunks = kG * (kH / 8);  // 524288
  convert_cell<<<2048, 256, 0, stream>>>(enc_Whh, wswz[0], wchunks);
  convert_cell<<<2048, 256, 0, stream>>>(enc_Wih + WL, wswz[1], wchunks);
  convert_cell<<<2048, 256, 0, stream>>>(enc_Whh + WL, wswz[2], wchunks);
  convert_cell<<<2048, 256, 0, stream>>>(dec_Whh, wswz[3], wchunks);
  convert_cell<<<2048, 256, 0, stream>>>(dec_Wih + WL, wswz[4], wchunks);
  convert_cell<<<2048, 256, 0, stream>>>(dec_Whh + WL, wswz[5], wchunks);
  convert_frag<<<2048, 256, 0, stream>>>(enc_Wih, wih0_enc, wchunks);
  convert_frag<<<2048, 256, 0, stream>>>(dec_Wih, wih0_dec, wchunks);

  // gather embeddings into A-frag layout
  gather_frag<<<128 * 8, 256, 0, stream>>>(enc_emb, input_ids, xin_enc, 128);
  gather_frag<<<126 * 8, 256, 0, stream>>>(dec_emb, output_ids, xin_dec, 126);

  // layer-0 input projections (bias fused, bf16 cell-order out)
  proj_mfma<<<dim3(32, 32), 256, 0, stream>>>(xin_enc, wih0_enc, enc_bih, enc_bhh,
                                              xproj_enc, 128);
  proj_mfma<<<dim3(32, 32), 256, 0, stream>>>(xin_dec, wih0_dec, dec_bih, dec_bhh,
                                              xproj_dec, 126);

  // ---- recurrence: ONE persistent kernel, 128 grid-sync'd iterations ----
  RecurArgs RA;
  RA.wih1[0] = wswz[1]; RA.wih1[1] = wswz[4];
  RA.whh1[0] = wswz[2]; RA.whh1[1] = wswz[5];
  RA.whh0[0] = wswz[0]; RA.whh0[1] = wswz[3];
  RA.xproj[0] = xproj_enc; RA.xproj[1] = xproj_dec;
  RA.bih1[0] = enc_bih + kG; RA.bih1[1] = dec_bih + kG;
  RA.bhh1[0] = enc_bhh + kG; RA.bhh1[1] = dec_bhh + kG;
  RA.c0 = c0; RA.c1 = c1;
  RA.h0[0] = h0swz[0]; RA.h0[1] = h0swz[1];
  RA.h1[0] = h1swz[0]; RA.h1[1] = h1swz[1];
  RA.htop = htop_frag;
  RA.flags = flags;
  lstm_persist<<<256, 512, 0, stream>>>(RA);

  // Wout frags (aliases xproj_enc region — must run after the recurrence)
  convert_frag<<<8000, 256, 0, stream>>>(Wout, wout_frag, kV * (kH / 8));

  // logits[:, 0, :]
  zero_t0_kernel<<<(kB * kV + 255) / 256, 256, 0, stream>>>(out);
  ones_t0_kernel<<<1, kB * kB, 0, stream>>>(output_ids, out);

  // logits[:, 1:, :]
  out_gemm_mfma<<<2016, 256, 0, stream>>>(htop_frag, wout_frag, bout, out);
}

// Round 9
// 1576.062 us; speedup vs baseline: 6.9112x; 6.9112x over previous
//
#include <hip/hip_runtime.h>

namespace {

constexpr int kB = 32;
constexpr int kT = 64;
constexpr int kH = 1024;
constexpr int kE = 1024;
constexpr int kV = 16000;
constexpr int kG = 4096;  // 4*H

typedef __attribute__((ext_vector_type(8))) short short8v;
typedef __attribute__((ext_vector_type(4))) float f32x4;

__device__ __forceinline__ float sigmoid_f(float x) {
  return 1.0f / (1.0f + __expf(-x));
}
__device__ __forceinline__ unsigned short f2bf(float x) {
  unsigned int u = __builtin_bit_cast(unsigned int, x);
  u = (u + 0x7FFFu + ((u >> 16) & 1u)) >> 16;
  return (unsigned short)u;
}
__device__ __forceinline__ float bf2f(unsigned short h) {
  return __builtin_bit_cast(float, (unsigned int)h << 16);
}

// ---------------- t=0 logits slice ----------------
__global__ void zero_t0_kernel(float* __restrict__ out) {
  int idx = blockIdx.x * blockDim.x + threadIdx.x;
  if (idx >= kB * kV) return;
  int b = idx / kV, v = idx % kV;
  __builtin_nontemporal_store(0.0f, &out[(size_t)b * kT * kV + v]);
}

// JAX outer-index semantics: out[b, 0, output_ids[j, 0]] = 1 for ALL (b, j)
__global__ void ones_t0_kernel(const int* __restrict__ output_ids,
                               float* __restrict__ out) {
  int b = threadIdx.x >> 5;
  int j = threadIdx.x & 31;
  int id = output_ids[j * kT];
  out[(size_t)b * kT * kV + id] = 1.0f;
}

// ---- convert fp32 row-major (R,1024) -> bf16 MFMA B-frag order, 16-row tiles.
__global__ __launch_bounds__(256)
void convert_frag(const float* __restrict__ src, unsigned short* __restrict__ dst,
                  int nchunks) {
  const int idx = blockIdx.x * 256 + threadIdx.x;
  if (idx >= nchunks) return;
  const int lane = idx & 63;
  const int s = (idx >> 6) & 31;
  const int rg = idx >> 11;
  const int row = rg * 16 + (lane & 15);
  const int k = s * 32 + ((lane >> 4) << 3);
  const float4* p = reinterpret_cast<const float4*>(src + (size_t)row * kH + k);
  float4 v0 = p[0], v1 = p[1];
  short8v o;
  o[0] = (short)f2bf(v0.x); o[1] = (short)f2bf(v0.y);
  o[2] = (short)f2bf(v0.z); o[3] = (short)f2bf(v0.w);
  o[4] = (short)f2bf(v1.x); o[5] = (short)f2bf(v1.y);
  o[6] = (short)f2bf(v1.z); o[7] = (short)f2bf(v1.w);
  *reinterpret_cast<short8v*>(dst + (size_t)idx * 8) = o;
}

// ---- convert fp32 gate-matrix (4096,1024) -> cell B-frag order.
// 16 n-cols = 4 gates x 4 units; quad q = ub*2+uq owns units 4q..4q+3.
__global__ __launch_bounds__(256)
void convert_cell(const float* __restrict__ src, unsigned short* __restrict__ dst,
                  int nchunks) {
  const int idx = blockIdx.x * 256 + threadIdx.x;
  if (idx >= nchunks) return;
  const int l = idx & 63;
  const int kstep = (idx >> 6) & 31;
  const int uq = (idx >> 11) & 1;
  const int ub = idx >> 12;
  const int n = l & 15;
  const int row = (n >> 2) * kH + ub * 8 + uq * 4 + (n & 3);
  const int k = kstep * 32 + ((l >> 4) << 3);
  const float4* p = reinterpret_cast<const float4*>(src + (size_t)row * kH + k);
  float4 v0 = p[0], v1 = p[1];
  short8v o;
  o[0] = (short)f2bf(v0.x); o[1] = (short)f2bf(v0.y);
  o[2] = (short)f2bf(v0.z); o[3] = (short)f2bf(v0.w);
  o[4] = (short)f2bf(v1.x); o[5] = (short)f2bf(v1.y);
  o[6] = (short)f2bf(v1.z); o[7] = (short)f2bf(v1.w);
  *reinterpret_cast<short8v*>(dst + (size_t)idx * 8) = o;
}

// ---- gather embedding rows into A-frag bf16 layout.
__global__ __launch_bounds__(256)
void gather_frag(const float* __restrict__ emb, const int* __restrict__ ids,
                 unsigned short* __restrict__ dst, int ntiles) {
  const int idx = blockIdx.x * 256 + threadIdx.x;
  const int lane = idx & 63;
  const int s = (idx >> 6) & 31;
  const int tile = idx >> 11;
  if (tile >= ntiles) return;
  const int m = tile * 16 + (lane & 15);
  const int t = m >> 5, b = m & 31;
  const int id = ids[b * kT + t];
  const int k = s * 32 + ((lane >> 4) << 3);
  const float4* p = reinterpret_cast<const float4*>(emb + (size_t)id * kE + k);
  float4 v0 = p[0], v1 = p[1];
  short8v o;
  o[0] = (short)f2bf(v0.x); o[1] = (short)f2bf(v0.y);
  o[2] = (short)f2bf(v0.z); o[3] = (short)f2bf(v0.w);
  o[4] = (short)f2bf(v1.x); o[5] = (short)f2bf(v1.y);
  o[6] = (short)f2bf(v1.z); o[7] = (short)f2bf(v1.w);
  *reinterpret_cast<short8v*>(dst + (size_t)idx * 8) = o;
}

// ---- proj MFMA: writes xproj in CELL-ORDER: [t][q][m 32][16 = g*4+uu] bf16,
// value = xin . W^T + b0 + b1.
__global__ __launch_bounds__(256)
void proj_mfma(const unsigned short* __restrict__ Af,
               const unsigned short* __restrict__ Bf,
               const float* __restrict__ b0, const float* __restrict__ b1,
               unsigned short* __restrict__ dst, int nmt) {
  const int w = threadIdx.x >> 6, lane = threadIdx.x & 63;
  const int mg = blockIdx.x, ng = blockIdx.y;
  f32x4 acc[4][2] = {};
  const unsigned short* Ab[4];
  const unsigned short* Bb[2];
#pragma unroll
  for (int i = 0; i < 4; ++i) {
    int tile = mg * 4 + i;
    if (tile > nmt - 1) tile = nmt - 1;
    Ab[i] = Af + (size_t)tile * 16384 + lane * 8;
  }
#pragma unroll
  for (int j = 0; j < 2; ++j) {
    const int nt = ng * 8 + w * 2 + j;
    Bb[j] = Bf + (size_t)nt * 16384 + lane * 8;
  }
#pragma unroll 2
  for (int s = 0; s < 32; ++s) {
    short8v a[4], b[2];
#pragma unroll
    for (int i = 0; i < 4; ++i) a[i] = *reinterpret_cast<const short8v*>(Ab[i] + s * 512);
#pragma unroll
    for (int j = 0; j < 2; ++j) b[j] = *reinterpret_cast<const short8v*>(Bb[j] + s * 512);
#pragma unroll
    for (int i = 0; i < 4; ++i)
#pragma unroll
      for (int j = 0; j < 2; ++j)
        acc[i][j] = __builtin_amdgcn_mfma_f32_16x16x32_bf16(a[i], b[j], acc[i][j], 0, 0, 0);
  }
#pragma unroll
  for (int i = 0; i < 4; ++i) {
    const int tile = mg * 4 + i;
    if (tile >= nmt) continue;
    const int mbase = tile * 16 + ((lane >> 4) << 2);
#pragma unroll
    for (int j = 0; j < 2; ++j) {
      const int n = (ng * 8 + w * 2 + j) * 16 + (lane & 15);
      const float bj = b0[n] + b1[n];
      const int g = n >> 10;
      const int u = n & 1023;
      const int q = u >> 2;
      const int uu = u & 3;
#pragma unroll
      for (int r = 0; r < 4; ++r) {
        const int m2 = mbase + r;
        const int t = m2 >> 5, mb = m2 & 31;
        dst[(size_t)t * kB * kG + (size_t)(q * 32 + mb) * 16 + g * 4 + uu] =
            f2bf(acc[i][j][r] + bj);
      }
    }
  }
}

// ---- output GEMM MFMA: XCD-swizzled 1-D grid; 4x4 tiles/wave; two-pass
// 32-row LDS transpose epilogue (33 KB) -> full-line f32x4 NT stores.
__global__ __launch_bounds__(256)
void out_gemm_mfma(const unsigned short* __restrict__ Af,
                   const unsigned short* __restrict__ Bf,
                   const float* __restrict__ bias, float* __restrict__ out) {
  const int w = threadIdx.x >> 6, lane = threadIdx.x & 63;
  // 2016 blocks = 8 XCDs x 252; give each XCD a contiguous swz-range so its
  // L2 holds one ~4MB Wout slice.
  const int bid = blockIdx.x;
  const int swz = (bid & 7) * 252 + (bid >> 3);
  const int mg = swz & 31, ng = swz >> 5;
  __shared__ float LsF[32 * 260];
  f32x4 acc[4][4] = {};
  const unsigned short* Ab[4];
  const unsigned short* Bb[4];
#pragma unroll
  for (int i = 0; i < 4; ++i) {
    int tile = mg * 4 + i;
    if (tile > 125) tile = 125;
    Ab[i] = Af + (size_t)tile * 16384 + lane * 8;
  }
#pragma unroll
  for (int j = 0; j < 4; ++j) {
    int nt = ng * 16 + w * 4 + j;
    if (nt > 999) nt = 999;
    Bb[j] = Bf + (size_t)nt * 16384 + lane * 8;
  }
#pragma unroll 2
  for (int s = 0; s < 32; ++s) {
    short8v a[4], b[4];
#pragma unroll
    for (int i = 0; i < 4; ++i) a[i] = *reinterpret_cast<const short8v*>(Ab[i] + s * 512);
#pragma unroll
    for (int j = 0; j < 4; ++j) b[j] = *reinterpret_cast<const short8v*>(Bb[j] + s * 512);
#pragma unroll
    for (int i = 0; i < 4; ++i)
#pragma unroll
      for (int j = 0; j < 4; ++j)
        acc[i][j] = __builtin_amdgcn_mfma_f32_16x16x32_bf16(a[i], b[j], acc[i][j], 0, 0, 0);
  }
  const int nglob = ng * 256 + lane * 4;
  f32x4 b4 = {0.f, 0.f, 0.f, 0.f};
  if (nglob < kV) b4 = *reinterpret_cast<const f32x4*>(&bias[nglob]);
#pragma unroll
  for (int ph = 0; ph < 2; ++ph) {
    if (ph) __syncthreads();
#pragma unroll
    for (int i2 = 0; i2 < 2; ++i2) {
      const int i = ph * 2 + i2;
      const int r2b = i2 * 16 + ((lane >> 4) << 2);
#pragma unroll
      for (int j = 0; j < 4; ++j) {
        const int nloc = (w * 4 + j) * 16 + (lane & 15);
#pragma unroll
        for (int r = 0; r < 4; ++r) LsF[(r2b + r) * 260 + nloc] = acc[i][j][r];
      }
    }
    __syncthreads();
    if (nglob < kV) {
#pragma unroll
      for (int it = 0; it < 8; ++it) {
        const int r2l = w * 8 + it;
        const int m = mg * 64 + ph * 32 + r2l;
        if (m >= 2016) break;
        f32x4 v = *reinterpret_cast<const f32x4*>(&LsF[r2l * 260 + lane * 4]);
        v += b4;
        const int sd = m >> 5, bb = m & 31;
        f32x4* dst = reinterpret_cast<f32x4*>(
            &out[(size_t)bb * kT * kV + (size_t)(sd + 1) * kV + nglob]);
        __builtin_nontemporal_store(v, dst);
      }
    }
  }
}

// ---- fused pair step: L1(p-1) and L0(p); 128 blocks x 512 thr.
// Block b owns unit-quads 2b,2b+1 (units 8b..8b+7) of BOTH layers. Each wave
// loads its K-slice of A ONCE and applies it to both quads' weights
// (12 MFMA/kstep) -> A traffic halved to 16 MB/step; weights (192 KB/block,
// 3 MB/XCD) read exactly once, L2-pinned across launches. 96 KB LDS reduce.
struct CellJob {
  const unsigned short* A0;      // H0[p-1] frags
  const unsigned short* A1;      // H1[p-2] frags
  const unsigned short* Wih1;    // cell layout (quad-indexed)
  const unsigned short* Whh1;
  const unsigned short* Whh0;
  const unsigned short* xprojc;  // cell-order slice for L0(p): [q][32][16]
  const float* bih1;             // layer-1 slice base (pre-offset +kG)
  const float* bhh1;
  float* c0;
  float* c1;
  unsigned short* h0_out;
  unsigned short* h1_out;
  unsigned short* htop_out;      // or null
  int has_l0, has_l1;
};

__global__ __launch_bounds__(512)
void lstm_pair(CellJob J) {
  const int blk = blockIdx.x;  // 0..127
  const int tid = threadIdx.x;
  const int wave = tid >> 6;   // K-slice 0..7
  const int lane = tid & 63;
  // Ls[quad][prod][wave][mt][lane][r]; prod: 0=ih1, 1=hh1, 2=hh0
  __shared__ alignas(16) float Ls[2][3][8][2][64][4];

  f32x4 aI[2][2] = {};  // [quad][mt]
  f32x4 aJ[2][2] = {};
  f32x4 aH[2][2] = {};
  const int ksb = wave * 4;
#pragma unroll
  for (int s = 0; s < 4; ++s) {
    const int ks = ksb + s;
    const short8v a00 =
        *reinterpret_cast<const short8v*>(J.A0 + (size_t)(ks * 64 + lane) * 8);
    const short8v a01 =
        *reinterpret_cast<const short8v*>(J.A0 + (size_t)((32 + ks) * 64 + lane) * 8);
    const short8v a10 =
        *reinterpret_cast<const short8v*>(J.A1 + (size_t)(ks * 64 + lane) * 8);
    const short8v a11 =
        *reinterpret_cast<const short8v*>(J.A1 + (size_t)((32 + ks) * 64 + lane) * 8);
#pragma unroll
    for (int qq = 0; qq < 2; ++qq) {
      const int q = blk * 2 + qq;
      const size_t widx = ((size_t)(q * 32 + ks) * 64 + lane) * 8;
      const short8v bi = *reinterpret_cast<const short8v*>(J.Wih1 + widx);
      aI[qq][0] = __builtin_amdgcn_mfma_f32_16x16x32_bf16(a00, bi, aI[qq][0], 0, 0, 0);
      aI[qq][1] = __builtin_amdgcn_mfma_f32_16x16x32_bf16(a01, bi, aI[qq][1], 0, 0, 0);
      const short8v bh1 = *reinterpret_cast<const short8v*>(J.Whh1 + widx);
      aJ[qq][0] = __builtin_amdgcn_mfma_f32_16x16x32_bf16(a10, bh1, aJ[qq][0], 0, 0, 0);
      aJ[qq][1] = __builtin_amdgcn_mfma_f32_16x16x32_bf16(a11, bh1, aJ[qq][1], 0, 0, 0);
      const short8v bh0 = *reinterpret_cast<const short8v*>(J.Whh0 + widx);
      aH[qq][0] = __builtin_amdgcn_mfma_f32_16x16x32_bf16(a00, bh0, aH[qq][0], 0, 0, 0);
      aH[qq][1] = __builtin_amdgcn_mfma_f32_16x16x32_bf16(a01, bh0, aH[qq][1], 0, 0, 0);
    }
  }
#pragma unroll
  for (int qq = 0; qq < 2; ++qq) {
#pragma unroll
    for (int mt = 0; mt < 2; ++mt) {
      *reinterpret_cast<f32x4*>(&Ls[qq][0][wave][mt][lane][0]) = aI[qq][mt];
      *reinterpret_cast<f32x4*>(&Ls[qq][1][wave][mt][lane][0]) = aJ[qq][mt];
      *reinterpret_cast<f32x4*>(&Ls[qq][2][wave][mt][lane][0]) = aH[qq][mt];
    }
  }
  __syncthreads();

  if (tid < 256) {
    const int qq = tid >> 7;        // quad within block
    const int m = (tid >> 2) & 31;  // batch row
    const int ul = tid & 3;         // unit within quad
    const int q = blk * 2 + qq;
    const int u = q * 4 + ul;
    const int mt = m >> 4, r = m & 3;
    const int lm = (m & 12) << 2;
    const int ksu = u >> 5;
    const int lane3 = (m & 15) | (((u >> 3) & 3) << 4);
    const int e = u & 7;
    const size_t fidx = (size_t)((mt * 32 + ksu) * 64 + lane3) * 8 + e;

    if (J.has_l0) {
      float g0[4];
#pragma unroll
      for (int g = 0; g < 4; ++g) {
        const int ln = (g * 4 + ul) | lm;
        float v = 0.f;
#pragma unroll
        for (int ww = 0; ww < 8; ++ww) v += Ls[qq][2][ww][mt][ln][r];
        v += bf2f(J.xprojc[(q * 32 + m) * 16 + g * 4 + ul]);
        g0[g] = v;
      }
      const float cold = J.c0[m * kH + u];
      const float cnew = sigmoid_f(g0[1]) * cold + sigmoid_f(g0[0]) * tanhf(g0[2]);
      const float hnew = sigmoid_f(g0[3]) * tanhf(cnew);
      J.c0[m * kH + u] = cnew;
      J.h0_out[fidx] = f2bf(hnew);
    }
    if (J.has_l1) {
      float g1[4];
#pragma unroll
      for (int g = 0; g < 4; ++g) {
        const int ln = (g * 4 + ul) | lm;
        float v = 0.f;
#pragma unroll
        for (int ww = 0; ww < 8; ++ww)
          v += Ls[qq][0][ww][mt][ln][r] + Ls[qq][1][ww][mt][ln][r];
        v += J.bih1[g * kH + u] + J.bhh1[g * kH + u];
        g1[g] = v;
      }
      const float cold = J.c1[m * kH + u];
      const float cnew = sigmoid_f(g1[1]) * cold + sigmoid_f(g1[0]) * tanhf(g1[2]);
      const float hnew = sigmoid_f(g1[3]) * tanhf(cnew);
      J.c1[m * kH + u] = cnew;
      const unsigned short hb = f2bf(hnew);
      J.h1_out[fidx] = hb;
      if (J.htop_out) J.htop_out[fidx] = hb;
    }
  }
}

}  // namespace

extern "C" void kernel_launch(void* const* d_in, const int* in_sizes, int n_in,
                              void* d_out, int out_size, void* d_ws, size_t ws_size,
                              hipStream_t stream) {
  const int* input_ids = (const int*)d_in[0];
  const int* output_ids = (const int*)d_in[1];
  const float* enc_emb = (const float*)d_in[2];
  const float* enc_Wih = (const float*)d_in[3];
  const float* enc_Whh = (const float*)d_in[4];
  const float* enc_bih = (const float*)d_in[5];
  const float* enc_bhh = (const float*)d_in[6];
  const float* dec_emb = (const float*)d_in[7];
  const float* dec_Wih = (const float*)d_in[8];
  const float* dec_Whh = (const float*)d_in[9];
  const float* dec_bih = (const float*)d_in[10];
  const float* dec_bhh = (const float*)d_in[11];
  const float* Wout = (const float*)d_in[12];
  const float* bout = (const float*)d_in[13];
  float* out = (float*)d_out;
  char* ws = (char*)d_ws;

  const size_t WL = (size_t)kG * kH;  // per-layer weight stride (elems)

  // ---- workspace layout (bytes) ----
  size_t off = 0;
  // Region dead after encoder; Wout frags alias here (32.77 MB < 37.75 MB)
  unsigned short* wout_frag = (unsigned short*)(ws + 0);
  unsigned short* xproj_enc = (unsigned short*)(ws + off); off += (size_t)kT * kB * kG * 2;
  unsigned short* xin_enc = (unsigned short*)(ws + off); off += (size_t)kT * kB * kH * 2;
  unsigned short* wih0_enc = (unsigned short*)(ws + off); off += WL * 2;
  unsigned short* wih0_dec = (unsigned short*)(ws + off); off += WL * 2;
  // persistent regions
  unsigned short* xproj_dec = (unsigned short*)(ws + off); off += (size_t)(kT - 1) * kB * kG * 2;
  unsigned short* xin_dec = (unsigned short*)(ws + off); off += (size_t)(kT - 1) * kB * kH * 2;
  unsigned short* htop_frag = xin_dec;  // alias: xin_dec dead before decoder starts
  float* c0 = (float*)(ws + off); off += (size_t)kB * kH * 4;
  float* c1 = (float*)(ws + off); off += (size_t)kB * kH * 4;
  unsigned short* h0swz[2];
  unsigned short* h1swz[2];
  h0swz[0] = (unsigned short*)(ws + off); off += (size_t)kB * kH * 2;
  h0swz[1] = (unsigned short*)(ws + off); off += (size_t)kB * kH * 2;
  h1swz[0] = (unsigned short*)(ws + off); off += (size_t)kB * kH * 2;
  h1swz[1] = (unsigned short*)(ws + off); off += (size_t)kB * kH * 2;
  unsigned short* wswz[6];
  for (int i = 0; i < 6; ++i) { wswz[i] = (unsigned short*)(ws + off); off += WL * 2; }

  // zero c0,c1 + h frag ping-pong buffers (contiguous)
  (void)hipMemsetAsync(c0, 0, (size_t)kB * kH * (4 + 4 + 2 + 2 + 2 + 2), stream);

  // one-time weight conversions
  const int wchunks = kG * (kH / 8);  // 524288
  convert_cell<<<2048, 256, 0, stream>>>(enc_Whh, wswz[0], wchunks);
  convert_cell<<<2048, 256, 0, stream>>>(enc_Wih + WL, wswz[1], wchunks);
  convert_cell<<<2048, 256, 0, stream>>>(enc_Whh + WL, wswz[2], wchunks);
  convert_cell<<<2048, 256, 0, stream>>>(dec_Whh, wswz[3], wchunks);
  convert_cell<<<2048, 256, 0, stream>>>(dec_Wih + WL, wswz[4], wchunks);
  convert_cell<<<2048, 256, 0, stream>>>(dec_Whh + WL, wswz[5], wchunks);
  convert_frag<<<2048, 256, 0, stream>>>(enc_Wih, wih0_enc, wchunks);
  convert_frag<<<2048, 256, 0, stream>>>(dec_Wih, wih0_dec, wchunks);

  // gather embeddings into A-frag layout
  gather_frag<<<128 * 8, 256, 0, stream>>>(enc_emb, input_ids, xin_enc, 128);
  gather_frag<<<126 * 8, 256, 0, stream>>>(dec_emb, output_ids, xin_dec, 126);

  // layer-0 input projections (bias fused, bf16 cell-order out)
  proj_mfma<<<dim3(32, 32), 256, 0, stream>>>(xin_enc, wih0_enc, enc_bih, enc_bhh,
                                              xproj_enc, 128);
  proj_mfma<<<dim3(32, 32), 256, 0, stream>>>(xin_dec, wih0_dec, dec_bih, dec_bhh,
                                              xproj_dec, 126);

  // ---- recurrence: launch p runs L1(p-1) and L0(p); 128 identical launches.
  for (int p = 0; p <= 127; ++p) {
    CellJob J = {};
    J.has_l0 = (p <= 126);
    J.has_l1 = (p >= 1);
    J.A0 = h0swz[p & 1];          // H0[p-1]
    J.A1 = h1swz[(p + 1) & 1];    // H1[p-2]
    J.c0 = c0;
    J.c1 = c1;
    if (J.has_l0) {
      J.Whh0 = (p < kT) ? wswz[0] : wswz[3];
      J.xprojc = (p < kT) ? (xproj_enc + (size_t)p * kB * kG)
                          : (xproj_dec + (size_t)(p - kT) * kB * kG);
      J.h0_out = h0swz[(p + 1) & 1];
    } else {
      J.Whh0 = wswz[3];  // unused but valid
      J.xprojc = xproj_dec;
      J.h0_out = h0swz[(p + 1) & 1];
    }
    if (J.has_l1) {
      const bool e1 = (p - 1) < kT;
      J.Wih1 = e1 ? wswz[1] : wswz[4];
      J.Whh1 = e1 ? wswz[2] : wswz[5];
      J.bih1 = (e1 ? enc_bih : dec_bih) + kG;
      J.bhh1 = (e1 ? enc_bhh : dec_bhh) + kG;
      J.h1_out = h1swz[p & 1];
      J.htop_out = (p - 1 >= kT) ? (htop_frag + (size_t)(p - 1 - kT) * kB * kH)
                                 : nullptr;
    } else {
      J.Wih1 = wswz[1];
      J.Whh1 = wswz[2];
      J.bih1 = enc_bih + kG;
      J.bhh1 = enc_bhh + kG;
      J.h1_out = h1swz[p & 1];
      J.htop_out = nullptr;
    }
    lstm_pair<<<128, 512, 0, stream>>>(J);
    if (p == 63) {
      // enc xproj fully consumed -> build Wout frags in the aliased region
      convert_frag<<<8000, 256, 0, stream>>>(Wout, wout_frag, kV * (kH / 8));
    }
  }

  // logits[:, 0, :]
  zero_t0_kernel<<<(kB * kV + 255) / 256, 256, 0, stream>>>(out);
  ones_t0_kernel<<<1, kB * kB, 0, stream>>>(output_ids, out);

  // logits[:, 1:, :]
  out_gemm_mfma<<<2016, 256, 0, stream>>>(htop_frag, wout_frag, bout, out);
}

// Round 10
// 1012.218 us; speedup vs baseline: 10.7611x; 1.5570x over previous
//
#include <hip/hip_runtime.h>

namespace {

constexpr int kB = 32;
constexpr int kT = 64;
constexpr int kH = 1024;
constexpr int kE = 1024;
constexpr int kV = 16000;
constexpr int kG = 4096;  // 4*H

typedef __attribute__((ext_vector_type(8))) short short8v;
typedef __attribute__((ext_vector_type(4))) float f32x4;

__device__ __forceinline__ float sigmoid_f(float x) {
  return 1.0f / (1.0f + __expf(-x));
}
__device__ __forceinline__ unsigned short f2bf(float x) {
  unsigned int u = __builtin_bit_cast(unsigned int, x);
  u = (u + 0x7FFFu + ((u >> 16) & 1u)) >> 16;
  return (unsigned short)u;
}
__device__ __forceinline__ float bf2f(unsigned short h) {
  return __builtin_bit_cast(float, (unsigned int)h << 16);
}

// ---------------- t=0 logits slice ----------------
__global__ void zero_t0_kernel(float* __restrict__ out) {
  int idx = blockIdx.x * blockDim.x + threadIdx.x;
  if (idx >= kB * kV) return;
  int b = idx / kV, v = idx % kV;
  __builtin_nontemporal_store(0.0f, &out[(size_t)b * kT * kV + v]);
}

// JAX outer-index semantics: out[b, 0, output_ids[j, 0]] = 1 for ALL (b, j)
__global__ void ones_t0_kernel(const int* __restrict__ output_ids,
                               float* __restrict__ out) {
  int b = threadIdx.x >> 5;
  int j = threadIdx.x & 31;
  int id = output_ids[j * kT];
  out[(size_t)b * kT * kV + id] = 1.0f;
}

// ---- fused one-time weight conversion: 8 matrices, mode 0=cell, 1=frag.
struct ConvJobs {
  const float* src[8];
  unsigned short* dst[8];
  int mode[8];
};
__global__ __launch_bounds__(256)
void conv8(ConvJobs C) {
  const int mat = blockIdx.x >> 11;
  const int idx = (blockIdx.x & 2047) * 256 + threadIdx.x;  // 0..524287
  const float* __restrict__ src = C.src[mat];
  unsigned short* __restrict__ dst = C.dst[mat];
  const int l = idx & 63;
  int row, k;
  if (C.mode[mat] == 0) {  // cell order
    const int kstep = (idx >> 6) & 31;
    const int uq = (idx >> 11) & 1;
    const int ub = idx >> 12;
    const int n = l & 15;
    row = (n >> 2) * kH + ub * 8 + uq * 4 + (n & 3);
    k = kstep * 32 + ((l >> 4) << 3);
  } else {  // frag order (16-row tiles)
    const int s = (idx >> 6) & 31;
    const int rg = idx >> 11;
    row = rg * 16 + (l & 15);
    k = s * 32 + ((l >> 4) << 3);
  }
  const float4* p = reinterpret_cast<const float4*>(src + (size_t)row * kH + k);
  float4 v0 = p[0], v1 = p[1];
  short8v o;
  o[0] = (short)f2bf(v0.x); o[1] = (short)f2bf(v0.y);
  o[2] = (short)f2bf(v0.z); o[3] = (short)f2bf(v0.w);
  o[4] = (short)f2bf(v1.x); o[5] = (short)f2bf(v1.y);
  o[6] = (short)f2bf(v1.z); o[7] = (short)f2bf(v1.w);
  *reinterpret_cast<short8v*>(dst + (size_t)idx * 8) = o;
}

// ---- convert fp32 row-major (R,1024) -> bf16 MFMA B-frag order (Wout).
__global__ __launch_bounds__(256)
void convert_frag(const float* __restrict__ src, unsigned short* __restrict__ dst,
                  int nchunks) {
  const int idx = blockIdx.x * 256 + threadIdx.x;
  if (idx >= nchunks) return;
  const int lane = idx & 63;
  const int s = (idx >> 6) & 31;
  const int rg = idx >> 11;
  const int row = rg * 16 + (lane & 15);
  const int k = s * 32 + ((lane >> 4) << 3);
  const float4* p = reinterpret_cast<const float4*>(src + (size_t)row * kH + k);
  float4 v0 = p[0], v1 = p[1];
  short8v o;
  o[0] = (short)f2bf(v0.x); o[1] = (short)f2bf(v0.y);
  o[2] = (short)f2bf(v0.z); o[3] = (short)f2bf(v0.w);
  o[4] = (short)f2bf(v1.x); o[5] = (short)f2bf(v1.y);
  o[6] = (short)f2bf(v1.z); o[7] = (short)f2bf(v1.w);
  *reinterpret_cast<short8v*>(dst + (size_t)idx * 8) = o;
}

// ---- combined L1 bias into cell order: dst[(u>>2)*16 + g*4 + (u&3)]
__global__ void bias_cell(const float* __restrict__ bih,
                          const float* __restrict__ bhh, float* __restrict__ dst) {
  const int i = blockIdx.x * 256 + threadIdx.x;
  if (i >= kG) return;
  const int g = i >> 10, u = i & 1023;
  dst[(u >> 2) * 16 + g * 4 + (u & 3)] = bih[i] + bhh[i];
}

// ---- gather embedding rows into A-frag bf16 layout.
__global__ __launch_bounds__(256)
void gather_frag(const float* __restrict__ emb, const int* __restrict__ ids,
                 unsigned short* __restrict__ dst, int ntiles) {
  const int idx = blockIdx.x * 256 + threadIdx.x;
  const int lane = idx & 63;
  const int s = (idx >> 6) & 31;
  const int tile = idx >> 11;
  if (tile >= ntiles) return;
  const int m = tile * 16 + (lane & 15);
  const int t = m >> 5, b = m & 31;
  const int id = ids[b * kT + t];
  const int k = s * 32 + ((lane >> 4) << 3);
  const float4* p = reinterpret_cast<const float4*>(emb + (size_t)id * kE + k);
  float4 v0 = p[0], v1 = p[1];
  short8v o;
  o[0] = (short)f2bf(v0.x); o[1] = (short)f2bf(v0.y);
  o[2] = (short)f2bf(v0.z); o[3] = (short)f2bf(v0.w);
  o[4] = (short)f2bf(v1.x); o[5] = (short)f2bf(v1.y);
  o[6] = (short)f2bf(v1.z); o[7] = (short)f2bf(v1.w);
  *reinterpret_cast<short8v*>(dst + (size_t)idx * 8) = o;
}

// ---- proj MFMA: writes xproj in CELL-ORDER: [t][q][m 32][16 = g*4+uu] bf16.
__global__ __launch_bounds__(256)
void proj_mfma(const unsigned short* __restrict__ Af,
               const unsigned short* __restrict__ Bf,
               const float* __restrict__ b0, const float* __restrict__ b1,
               unsigned short* __restrict__ dst, int nmt) {
  const int w = threadIdx.x >> 6, lane = threadIdx.x & 63;
  const int mg = blockIdx.x, ng = blockIdx.y;
  f32x4 acc[4][2] = {};
  const unsigned short* Ab[4];
  const unsigned short* Bb[2];
#pragma unroll
  for (int i = 0; i < 4; ++i) {
    int tile = mg * 4 + i;
    if (tile > nmt - 1) tile = nmt - 1;
    Ab[i] = Af + (size_t)tile * 16384 + lane * 8;
  }
#pragma unroll
  for (int j = 0; j < 2; ++j) {
    const int nt = ng * 8 + w * 2 + j;
    Bb[j] = Bf + (size_t)nt * 16384 + lane * 8;
  }
#pragma unroll 2
  for (int s = 0; s < 32; ++s) {
    short8v a[4], b[2];
#pragma unroll
    for (int i = 0; i < 4; ++i) a[i] = *reinterpret_cast<const short8v*>(Ab[i] + s * 512);
#pragma unroll
    for (int j = 0; j < 2; ++j) b[j] = *reinterpret_cast<const short8v*>(Bb[j] + s * 512);
#pragma unroll
    for (int i = 0; i < 4; ++i)
#pragma unroll
      for (int j = 0; j < 2; ++j)
        acc[i][j] = __builtin_amdgcn_mfma_f32_16x16x32_bf16(a[i], b[j], acc[i][j], 0, 0, 0);
  }
#pragma unroll
  for (int i = 0; i < 4; ++i) {
    const int tile = mg * 4 + i;
    if (tile >= nmt) continue;
    const int mbase = tile * 16 + ((lane >> 4) << 2);
#pragma unroll
    for (int j = 0; j < 2; ++j) {
      const int n = (ng * 8 + w * 2 + j) * 16 + (lane & 15);
      const float bj = b0[n] + b1[n];
      const int g = n >> 10;
      const int u = n & 1023;
      const int q = u >> 2;
      const int uu = u & 3;
#pragma unroll
      for (int r = 0; r < 4; ++r) {
        const int m2 = mbase + r;
        const int t = m2 >> 5, mb = m2 & 31;
        dst[(size_t)t * kB * kG + (size_t)(q * 32 + mb) * 16 + g * 4 + uu] =
            f2bf(acc[i][j][r] + bj);
      }
    }
  }
}

// ---- output GEMM MFMA: XCD-swizzled 1-D grid; 4x4 tiles/wave; two-pass
// 32-row LDS transpose epilogue (33 KB) -> full-line f32x4 NT stores.
__global__ __launch_bounds__(256)
void out_gemm_mfma(const unsigned short* __restrict__ Af,
                   const unsigned short* __restrict__ Bf,
                   const float* __restrict__ bias, float* __restrict__ out) {
  const int w = threadIdx.x >> 6, lane = threadIdx.x & 63;
  const int bid = blockIdx.x;
  const int swz = (bid & 7) * 252 + (bid >> 3);
  const int mg = swz & 31, ng = swz >> 5;
  __shared__ float LsF[32 * 260];
  f32x4 acc[4][4] = {};
  const unsigned short* Ab[4];
  const unsigned short* Bb[4];
#pragma unroll
  for (int i = 0; i < 4; ++i) {
    int tile = mg * 4 + i;
    if (tile > 125) tile = 125;
    Ab[i] = Af + (size_t)tile * 16384 + lane * 8;
  }
#pragma unroll
  for (int j = 0; j < 4; ++j) {
    int nt = ng * 16 + w * 4 + j;
    if (nt > 999) nt = 999;
    Bb[j] = Bf + (size_t)nt * 16384 + lane * 8;
  }
#pragma unroll 2
  for (int s = 0; s < 32; ++s) {
    short8v a[4], b[4];
#pragma unroll
    for (int i = 0; i < 4; ++i) a[i] = *reinterpret_cast<const short8v*>(Ab[i] + s * 512);
#pragma unroll
    for (int j = 0; j < 4; ++j) b[j] = *reinterpret_cast<const short8v*>(Bb[j] + s * 512);
#pragma unroll
    for (int i = 0; i < 4; ++i)
#pragma unroll
      for (int j = 0; j < 4; ++j)
        acc[i][j] = __builtin_amdgcn_mfma_f32_16x16x32_bf16(a[i], b[j], acc[i][j], 0, 0, 0);
  }
  const int nglob = ng * 256 + lane * 4;
  f32x4 b4 = {0.f, 0.f, 0.f, 0.f};
  if (nglob < kV) b4 = *reinterpret_cast<const f32x4*>(&bias[nglob]);
#pragma unroll
  for (int ph = 0; ph < 2; ++ph) {
    if (ph) __syncthreads();
#pragma unroll
    for (int i2 = 0; i2 < 2; ++i2) {
      const int i = ph * 2 + i2;
      const int r2b = i2 * 16 + ((lane >> 4) << 2);
#pragma unroll
      for (int j = 0; j < 4; ++j) {
        const int nloc = (w * 4 + j) * 16 + (lane & 15);
#pragma unroll
        for (int r = 0; r < 4; ++r) LsF[(r2b + r) * 260 + nloc] = acc[i][j][r];
      }
    }
    __syncthreads();
    if (nglob < kV) {
#pragma unroll
      for (int it = 0; it < 8; ++it) {
        const int r2l = w * 8 + it;
        const int m = mg * 64 + ph * 32 + r2l;
        if (m >= 2016) break;
        f32x4 v = *reinterpret_cast<const f32x4*>(&LsF[r2l * 260 + lane * 4]);
        v += b4;
        const int sd = m >> 5, bb = m & 31;
        f32x4* dst = reinterpret_cast<f32x4*>(
            &out[(size_t)bb * kT * kV + (size_t)(sd + 1) * kV + nglob]);
        __builtin_nontemporal_store(v, dst);
      }
    }
  }
}

// ---- fused pair step: 512 blocks x 256 thr; block = (quad q, batch-half mt).
// XCD-pinned: q = (bid&7)*32 + ((bid>>3)>>1), mt = (bid>>3)&1 keeps both
// mt-blocks of a quad on one XCD (3 MB weights/XCD, L2-resident across
// launches). 4 waves x K=256; epilogue operands prefetched pre-MFMA.
struct CellJob {
  const unsigned short* A0;      // H0[p-1] frags
  const unsigned short* A1;      // H1[p-2] frags
  const unsigned short* Wih1;    // cell layout
  const unsigned short* Whh1;
  const unsigned short* Whh0;
  const unsigned short* xprojc;  // cell-order slice for L0(p)
  const float* bsum1;            // cell-order combined L1 bias [q*16+g*4+ul]
  float* c0;
  float* c1;
  unsigned short* h0_out;
  unsigned short* h1_out;
  unsigned short* htop_out;      // or null
  int has_l0, has_l1;
};

__global__ __launch_bounds__(256)
void lstm_pair(CellJob J) {
  const int bid = blockIdx.x;                 // 0..511
  const int q = (bid & 7) * 32 + ((bid >> 3) >> 1);
  const int mt = (bid >> 3) & 1;
  const int tid = threadIdx.x;
  const int wave = tid >> 6;                  // K-slice 0..3
  const int lane = tid & 63;
  // Ls[prod][wave][lane][r]; prod: 0=ih1, 1=hh1, 2=hh0
  __shared__ alignas(16) float Ls[3][4][64][4];  // 12 KB

  // ---- epilogue operand prefetch (wave 0 only; uniform per wave) ----
  const int mloc = tid >> 2;  // valid for tid<64
  const int ul = tid & 3;
  const int m = mt * 16 + (mloc & 15);
  const int u = q * 4 + ul;
  float cold0 = 0.f, cold1 = 0.f;
  float xp[4] = {}, bs[4] = {};
  if (tid < 64) {
    cold0 = J.c0[m * kH + u];
    cold1 = J.c1[m * kH + u];
#pragma unroll
    for (int g = 0; g < 4; ++g) {
      xp[g] = bf2f(J.xprojc[(q * 32 + m) * 16 + g * 4 + ul]);
      bs[g] = J.bsum1[q * 16 + g * 4 + ul];
    }
  }

  f32x4 aI = {0.f, 0.f, 0.f, 0.f};
  f32x4 aJv = {0.f, 0.f, 0.f, 0.f};
  f32x4 aH = {0.f, 0.f, 0.f, 0.f};
  const int ksb = wave * 8;
#pragma unroll
  for (int s = 0; s < 8; ++s) {
    const int ks = ksb + s;
    const size_t aidx = (size_t)((mt * 32 + ks) * 64 + lane) * 8;
    const size_t widx = ((size_t)(q * 32 + ks) * 64 + lane) * 8;
    const short8v a0 = *reinterpret_cast<const short8v*>(J.A0 + aidx);
    const short8v a1 = *reinterpret_cast<const short8v*>(J.A1 + aidx);
    const short8v bi = *reinterpret_cast<const short8v*>(J.Wih1 + widx);
    const short8v bh1 = *reinterpret_cast<const short8v*>(J.Whh1 + widx);
    const short8v bh0 = *reinterpret_cast<const short8v*>(J.Whh0 + widx);
    aI = __builtin_amdgcn_mfma_f32_16x16x32_bf16(a0, bi, aI, 0, 0, 0);
    aJv = __builtin_amdgcn_mfma_f32_16x16x32_bf16(a1, bh1, aJv, 0, 0, 0);
    aH = __builtin_amdgcn_mfma_f32_16x16x32_bf16(a0, bh0, aH, 0, 0, 0);
  }
  *reinterpret_cast<f32x4*>(&Ls[0][wave][lane][0]) = aI;
  *reinterpret_cast<f32x4*>(&Ls[1][wave][lane][0]) = aJv;
  *reinterpret_cast<f32x4*>(&Ls[2][wave][lane][0]) = aH;
  __syncthreads();

  if (tid < 64) {
    const int r = mloc & 3;
    const int lm = (mloc & 12) << 2;
    const int ksu = u >> 5;
    const int lane3 = (m & 15) | (((u >> 3) & 3) << 4);
    const int e = u & 7;
    const size_t fidx = (size_t)((mt * 32 + ksu) * 64 + lane3) * 8 + e;

    if (J.has_l0) {
      float g0[4];
#pragma unroll
      for (int g = 0; g < 4; ++g) {
        const int ln = (g * 4 + ul) | lm;
        g0[g] = Ls[2][0][ln][r] + Ls[2][1][ln][r] + Ls[2][2][ln][r] +
                Ls[2][3][ln][r] + xp[g];
      }
      const float cnew = sigmoid_f(g0[1]) * cold0 + sigmoid_f(g0[0]) * tanhf(g0[2]);
      const float hnew = sigmoid_f(g0[3]) * tanhf(cnew);
      J.c0[m * kH + u] = cnew;
      J.h0_out[fidx] = f2bf(hnew);
    }
    if (J.has_l1) {
      float g1[4];
#pragma unroll
      for (int g = 0; g < 4; ++g) {
        const int ln = (g * 4 + ul) | lm;
        g1[g] = Ls[0][0][ln][r] + Ls[0][1][ln][r] + Ls[0][2][ln][r] +
                Ls[0][3][ln][r] + Ls[1][0][ln][r] + Ls[1][1][ln][r] +
                Ls[1][2][ln][r] + Ls[1][3][ln][r] + bs[g];
      }
      const float cnew = sigmoid_f(g1[1]) * cold1 + sigmoid_f(g1[0]) * tanhf(g1[2]);
      const float hnew = sigmoid_f(g1[3]) * tanhf(cnew);
      J.c1[m * kH + u] = cnew;
      const unsigned short hb = f2bf(hnew);
      J.h1_out[fidx] = hb;
      if (J.htop_out) J.htop_out[fidx] = hb;
    }
  }
}

}  // namespace

extern "C" void kernel_launch(void* const* d_in, const int* in_sizes, int n_in,
                              void* d_out, int out_size, void* d_ws, size_t ws_size,
                              hipStream_t stream) {
  const int* input_ids = (const int*)d_in[0];
  const int* output_ids = (const int*)d_in[1];
  const float* enc_emb = (const float*)d_in[2];
  const float* enc_Wih = (const float*)d_in[3];
  const float* enc_Whh = (const float*)d_in[4];
  const float* enc_bih = (const float*)d_in[5];
  const float* enc_bhh = (const float*)d_in[6];
  const float* dec_emb = (const float*)d_in[7];
  const float* dec_Wih = (const float*)d_in[8];
  const float* dec_Whh = (const float*)d_in[9];
  const float* dec_bih = (const float*)d_in[10];
  const float* dec_bhh = (const float*)d_in[11];
  const float* Wout = (const float*)d_in[12];
  const float* bout = (const float*)d_in[13];
  float* out = (float*)d_out;
  char* ws = (char*)d_ws;

  const size_t WL = (size_t)kG * kH;  // per-layer weight stride (elems)

  // ---- workspace layout (bytes) ----
  size_t off = 0;
  // Region dead after encoder; Wout frags alias here (32.77 MB < 37.75 MB)
  unsigned short* wout_frag = (unsigned short*)(ws + 0);
  unsigned short* xproj_enc = (unsigned short*)(ws + off); off += (size_t)kT * kB * kG * 2;
  unsigned short* xin_enc = (unsigned short*)(ws + off); off += (size_t)kT * kB * kH * 2;
  unsigned short* wih0_enc = (unsigned short*)(ws + off); off += WL * 2;
  unsigned short* wih0_dec = (unsigned short*)(ws + off); off += WL * 2;
  // persistent regions
  unsigned short* xproj_dec = (unsigned short*)(ws + off); off += (size_t)(kT - 1) * kB * kG * 2;
  unsigned short* xin_dec = (unsigned short*)(ws + off); off += (size_t)(kT - 1) * kB * kH * 2;
  unsigned short* htop_frag = xin_dec;  // alias: xin_dec dead before decoder starts
  float* c0 = (float*)(ws + off); off += (size_t)kB * kH * 4;
  float* c1 = (float*)(ws + off); off += (size_t)kB * kH * 4;
  unsigned short* h0swz[2];
  unsigned short* h1swz[2];
  h0swz[0] = (unsigned short*)(ws + off); off += (size_t)kB * kH * 2;
  h0swz[1] = (unsigned short*)(ws + off); off += (size_t)kB * kH * 2;
  h1swz[0] = (unsigned short*)(ws + off); off += (size_t)kB * kH * 2;
  h1swz[1] = (unsigned short*)(ws + off); off += (size_t)kB * kH * 2;
  unsigned short* wswz[6];
  for (int i = 0; i < 6; ++i) { wswz[i] = (unsigned short*)(ws + off); off += WL * 2; }
  float* bsum_enc = (float*)(ws + off); off += kG * 4;
  float* bsum_dec = (float*)(ws + off); off += kG * 4;

  // zero c0,c1 + h frag ping-pong buffers (contiguous)
  (void)hipMemsetAsync(c0, 0, (size_t)kB * kH * (4 + 4 + 2 + 2 + 2 + 2), stream);

  // one-time weight conversions (single fused launch)
  ConvJobs C;
  C.src[0] = enc_Whh;       C.dst[0] = wswz[0];    C.mode[0] = 0;
  C.src[1] = enc_Wih + WL;  C.dst[1] = wswz[1];    C.mode[1] = 0;
  C.src[2] = enc_Whh + WL;  C.dst[2] = wswz[2];    C.mode[2] = 0;
  C.src[3] = dec_Whh;       C.dst[3] = wswz[3];    C.mode[3] = 0;
  C.src[4] = dec_Wih + WL;  C.dst[4] = wswz[4];    C.mode[4] = 0;
  C.src[5] = dec_Whh + WL;  C.dst[5] = wswz[5];    C.mode[5] = 0;
  C.src[6] = enc_Wih;       C.dst[6] = wih0_enc;   C.mode[6] = 1;
  C.src[7] = dec_Wih;       C.dst[7] = wih0_dec;   C.mode[7] = 1;
  conv8<<<8 * 2048, 256, 0, stream>>>(C);
  bias_cell<<<16, 256, 0, stream>>>(enc_bih + kG, enc_bhh + kG, bsum_enc);
  bias_cell<<<16, 256, 0, stream>>>(dec_bih + kG, dec_bhh + kG, bsum_dec);

  // gather embeddings into A-frag layout
  gather_frag<<<128 * 8, 256, 0, stream>>>(enc_emb, input_ids, xin_enc, 128);
  gather_frag<<<126 * 8, 256, 0, stream>>>(dec_emb, output_ids, xin_dec, 126);

  // layer-0 input projections (bias fused, bf16 cell-order out)
  proj_mfma<<<dim3(32, 32), 256, 0, stream>>>(xin_enc, wih0_enc, enc_bih, enc_bhh,
                                              xproj_enc, 128);
  proj_mfma<<<dim3(32, 32), 256, 0, stream>>>(xin_dec, wih0_dec, dec_bih, dec_bhh,
                                              xproj_dec, 126);

  // ---- recurrence: launch p runs L1(p-1) and L0(p); 128 identical launches.
  for (int p = 0; p <= 127; ++p) {
    CellJob J = {};
    J.has_l0 = (p <= 126);
    J.has_l1 = (p >= 1);
    J.A0 = h0swz[p & 1];          // H0[p-1]
    J.A1 = h1swz[(p + 1) & 1];    // H1[p-2]
    J.c0 = c0;
    J.c1 = c1;
    J.h0_out = h0swz[(p + 1) & 1];
    J.h1_out = h1swz[p & 1];
    // L0(p) operands (valid pointers even when gated off)
    if (p <= 126) {
      J.Whh0 = (p < kT) ? wswz[0] : wswz[3];
      J.xprojc = (p < kT) ? (xproj_enc + (size_t)p * kB * kG)
                          : (xproj_dec + (size_t)(p - kT) * kB * kG);
    } else {
      J.Whh0 = wswz[3];
      J.xprojc = xproj_dec;
    }
    // L1(p-1) operands
    const bool e1 = (p - 1) < kT;
    J.Wih1 = (p >= 1 && !e1) ? wswz[4] : wswz[1];
    J.Whh1 = (p >= 1 && !e1) ? wswz[5] : wswz[2];
    J.bsum1 = (p >= 1 && !e1) ? bsum_dec : bsum_enc;
    J.htop_out = (p >= 1 && (p - 1) >= kT)
                     ? (htop_frag + (size_t)(p - 1 - kT) * kB * kH)
                     : nullptr;
    lstm_pair<<<512, 256, 0, stream>>>(J);
    if (p == 63) {
      // enc xproj fully consumed -> build Wout frags in the aliased region
      convert_frag<<<8000, 256, 0, stream>>>(Wout, wout_frag, kV * (kH / 8));
    }
  }

  // logits[:, 0, :]
  zero_t0_kernel<<<(kB * kV + 255) / 256, 256, 0, stream>>>(out);
  ones_t0_kernel<<<1, kB * kB, 0, stream>>>(output_ids, out);

  // logits[:, 1:, :]
  out_gemm_mfma<<<2016, 256, 0, stream>>>(htop_frag, wout_frag, bout, out);
}